// Round 6
// baseline (91.657 us; speedup 1.0000x reference)
//
#include <hip/hip_runtime.h>
#include <math.h>

#define DD 2048
#define DTC 0.01f
#define NSTEPS 30
#define ROWS 4

typedef float floatx4 __attribute__((ext_vector_type(4)));

__device__ __forceinline__ void lorenz_deriv(float x, float y, float z,
                                             float sigma, float rho, float beta,
                                             float& dx, float& dy, float& dz) {
    dx = sigma * (y - x);
    dy = x * (rho - z) - y;
    dz = x * y - beta * z;
}

__device__ __forceinline__ float fast_tanh(float p) {
    float e = __expf(2.0f * p);
    return 1.0f - __fdividef(2.0f, e + 1.0f);
}

// Prologue: transpose W_out[2048][18] -> wsT[18][2048] (coalesced writes).
__global__ __launch_bounds__(256) void k_transpose(const float* __restrict__ W_out,
                                                   float* __restrict__ wsT) {
    const int oidx = blockIdx.x * 256 + threadIdx.x;   // 144 blocks * 256 = 36864
    const int k = oidx >> 11;         // / 2048
    const int c = oidx & 2047;
    wsT[oidx] = W_out[c * 18 + k];
}

// Fused: 4 rows/block, 256 threads, thread owns 8 consecutive cols.
// x lives in registers from the dot-product phase through the epilogue.
__global__ __launch_bounds__(256, 4) void fused2(
    const float* __restrict__ x, const float* __restrict__ lorenz,
    const float* __restrict__ W_in, const float* __restrict__ b_in,
    const float* __restrict__ wsT, const float* __restrict__ b_out,
    const float* __restrict__ strength, float* __restrict__ out) {
    __shared__ float red[4][ROWS * 3];
    __shared__ float feats_lds[ROWS][18];

    const int tid = threadIdx.x;
    const int lane = tid & 63;
    const int wv = tid >> 6;
    const int row0 = blockIdx.x * ROWS;
    const int c0 = tid * 8;

    // x tile -> registers (4 rows x 8 cols/thread)
    floatx4 xva[ROWS], xvb[ROWS];
#pragma unroll
    for (int r = 0; r < ROWS; ++r) {
        const float* p = x + (size_t)(row0 + r) * DD + c0;
        xva[r] = *reinterpret_cast<const floatx4*>(p);
        xvb[r] = *reinterpret_cast<const floatx4*>(p + 4);
    }

    // W_in slice (3 x 8 cols)
    floatx4 wa0, wb0, wa1, wb1, wa2, wb2;
    {
        const float* p0 = W_in + 0 * DD + c0;
        const float* p1 = W_in + 1 * DD + c0;
        const float* p2 = W_in + 2 * DD + c0;
        wa0 = *reinterpret_cast<const floatx4*>(p0); wb0 = *reinterpret_cast<const floatx4*>(p0 + 4);
        wa1 = *reinterpret_cast<const floatx4*>(p1); wb1 = *reinterpret_cast<const floatx4*>(p1 + 4);
        wa2 = *reinterpret_cast<const floatx4*>(p2); wb2 = *reinterpret_cast<const floatx4*>(p2 + 4);
    }

    // Partial dots, then wave shfl-reduce, then cross-wave via LDS.
#pragma unroll
    for (int r = 0; r < ROWS; ++r) {
        floatx4 s0 = xva[r] * wa0 + xvb[r] * wb0;
        floatx4 s1 = xva[r] * wa1 + xvb[r] * wb1;
        floatx4 s2 = xva[r] * wa2 + xvb[r] * wb2;
        float v0 = s0.x + s0.y + s0.z + s0.w;
        float v1 = s1.x + s1.y + s1.z + s1.w;
        float v2 = s2.x + s2.y + s2.z + s2.w;
#pragma unroll
        for (int off = 32; off > 0; off >>= 1) {
            v0 += __shfl_xor(v0, off, 64);
            v1 += __shfl_xor(v1, off, 64);
            v2 += __shfl_xor(v2, off, 64);
        }
        if (lane == 0) {
            red[wv][r * 3 + 0] = v0;
            red[wv][r * 3 + 1] = v1;
            red[wv][r * 3 + 2] = v2;
        }
    }
    __syncthreads();

    // Integrating wave (rotates per block): combine partials + RK4 + stats.
    if (wv == (int)(blockIdx.x & 3)) {
        float v = 0.0f;
        if (lane < ROWS * 3) {
            v = red[0][lane] + red[1][lane] + red[2][lane] + red[3][lane]
                + b_in[lane % 3];
        }
        // gather this lane's row state (lanes 0..ROWS-1 used)
        float sx = __shfl(v, lane * 3 + 0, 64);
        float sy = __shfl(v, lane * 3 + 1, 64);
        float sz = __shfl(v, lane * 3 + 2, 64);
        if (lane < ROWS) {
            const float sigma = fmaxf(fabsf(lorenz[0]), 0.1f);
            const float rho   = fmaxf(fabsf(lorenz[1]), 0.1f);
            const float beta  = fmaxf(fabsf(lorenz[2]), 0.1f);
            const float ix = sx, iy = sy, iz = sz;
            float sux = sx, suy = sy, suz = sz;
            float sqx = sx * sx, sqy = sy * sy, sqz = sz * sz;
            float mnx = sx, mny = sy, mnz = sz;
            float mxx = sx, mxy = sy, mxz = sz;
#pragma unroll 1
            for (int t = 0; t < NSTEPS; ++t) {
                float k1x, k1y, k1z, k2x, k2y, k2z, k3x, k3y, k3z, k4x, k4y, k4z;
                float ax, ay, az;
                lorenz_deriv(sx, sy, sz, sigma, rho, beta, k1x, k1y, k1z);
                ax = sx + 0.5f * DTC * k1x; ay = sy + 0.5f * DTC * k1y; az = sz + 0.5f * DTC * k1z;
                lorenz_deriv(ax, ay, az, sigma, rho, beta, k2x, k2y, k2z);
                ax = sx + 0.5f * DTC * k2x; ay = sy + 0.5f * DTC * k2y; az = sz + 0.5f * DTC * k2z;
                lorenz_deriv(ax, ay, az, sigma, rho, beta, k3x, k3y, k3z);
                ax = sx + DTC * k3x; ay = sy + DTC * k3y; az = sz + DTC * k3z;
                lorenz_deriv(ax, ay, az, sigma, rho, beta, k4x, k4y, k4z);
                sx += (DTC / 6.0f) * (k1x + 2.0f * k2x + 2.0f * k3x + k4x);
                sy += (DTC / 6.0f) * (k1y + 2.0f * k2y + 2.0f * k3y + k4y);
                sz += (DTC / 6.0f) * (k1z + 2.0f * k2z + 2.0f * k3z + k4z);
                sux += sx; suy += sy; suz += sz;
                sqx += sx * sx; sqy += sy * sy; sqz += sz * sz;
                mnx = fminf(mnx, sx); mny = fminf(mny, sy); mnz = fminf(mnz, sz);
                mxx = fmaxf(mxx, sx); mxy = fmaxf(mxy, sy); mxz = fmaxf(mxz, sz);
            }
            const float inv31 = 1.0f / 31.0f;
            const float inv30 = 1.0f / 30.0f;
            const float mex = sux * inv31, mey = suy * inv31, mez = suz * inv31;
            const float vax = fmaxf((sqx - sux * mex) * inv30, 0.0f);
            const float vay = fmaxf((sqy - suy * mey) * inv30, 0.0f);
            const float vaz = fmaxf((sqz - suz * mez) * inv30, 0.0f);
            float* f = feats_lds[lane];
            f[0]  = ix;  f[1]  = iy;  f[2]  = iz;
            f[3]  = sx;  f[4]  = sy;  f[5]  = sz;
            f[6]  = mex; f[7]  = mey; f[8]  = mez;
            f[9]  = sqrtf(vax); f[10] = sqrtf(vay); f[11] = sqrtf(vaz);
            f[12] = mnx; f[13] = mny; f[14] = mnz;
            f[15] = mxx; f[16] = mxy; f[17] = mxz;
        }
    }
    __syncthreads();

    // Epilogue: pert = feats @ W_out^T via transposed weights (coalesced),
    // feats broadcast from LDS, x from registers, NT stores.
    const float sabs = fabsf(strength[0]);
    floatx4 pa[ROWS], pb[ROWS];
    {
        const floatx4 boa = *reinterpret_cast<const floatx4*>(b_out + c0);
        const floatx4 bob = *reinterpret_cast<const floatx4*>(b_out + c0 + 4);
#pragma unroll
        for (int r = 0; r < ROWS; ++r) { pa[r] = boa; pb[r] = bob; }
    }
#pragma unroll
    for (int k = 0; k < 18; ++k) {
        const float* wp = wsT + k * DD + c0;
        const floatx4 wka = *reinterpret_cast<const floatx4*>(wp);
        const floatx4 wkb = *reinterpret_cast<const floatx4*>(wp + 4);
#pragma unroll
        for (int r = 0; r < ROWS; ++r) {
            const float fk = feats_lds[r][k];
            pa[r] += fk * wka;
            pb[r] += fk * wkb;
        }
    }
#pragma unroll
    for (int r = 0; r < ROWS; ++r) {
        floatx4 oa, ob;
        oa.x = xva[r].x + fast_tanh(pa[r].x) * sabs;
        oa.y = xva[r].y + fast_tanh(pa[r].y) * sabs;
        oa.z = xva[r].z + fast_tanh(pa[r].z) * sabs;
        oa.w = xva[r].w + fast_tanh(pa[r].w) * sabs;
        ob.x = xvb[r].x + fast_tanh(pb[r].x) * sabs;
        ob.y = xvb[r].y + fast_tanh(pb[r].y) * sabs;
        ob.z = xvb[r].z + fast_tanh(pb[r].z) * sabs;
        ob.w = xvb[r].w + fast_tanh(pb[r].w) * sabs;
        float* op = out + (size_t)(row0 + r) * DD + c0;
        __builtin_nontemporal_store(oa, reinterpret_cast<floatx4*>(op));
        __builtin_nontemporal_store(ob, reinterpret_cast<floatx4*>(op + 4));
    }
}

extern "C" void kernel_launch(void* const* d_in, const int* in_sizes, int n_in,
                              void* d_out, int out_size, void* d_ws, size_t ws_size,
                              hipStream_t stream) {
    const float* x        = (const float*)d_in[0];
    const float* lorenz   = (const float*)d_in[1];
    const float* strength = (const float*)d_in[2];
    const float* W_in     = (const float*)d_in[3];
    const float* b_in     = (const float*)d_in[4];
    const float* W_out    = (const float*)d_in[5];
    const float* b_out    = (const float*)d_in[6];
    float* out = (float*)d_out;
    float* wsT = (float*)d_ws;   // 18*2048 floats = 147 KB

    const int N = in_sizes[0] / DD;  // 16384

    k_transpose<<<(18 * DD) / 256, 256, 0, stream>>>(W_out, wsT);
    fused2<<<N / ROWS, 256, 0, stream>>>(
        x, lorenz, W_in, b_in, wsT, b_out, strength, out);
}